// Round 7
// baseline (204.828 us; speedup 1.0000x reference)
//
#include <hip/hip_runtime.h>
#include <hip/hip_bf16.h>

#define HWN 9216              // 96*96
#define PLN (64 * HWN)        // one frame's feature plane (C=64)

typedef __attribute__((ext_vector_type(8))) short bf16x8;
typedef __attribute__((ext_vector_type(4))) float f32x4;

__device__ __forceinline__ unsigned short f2bf(float v) {
    union { float f; unsigned u; } cv; cv.f = v;
    unsigned u = cv.u;
    u += 0x7fffu + ((u >> 16) & 1u);   // round-to-nearest-even
    return (unsigned short)(u >> 16);
}
__device__ __forceinline__ float bf2f(unsigned short b) {
    union { unsigned u; float f; } cv; cv.u = ((unsigned)b) << 16;
    return cv.f;
}
__device__ __forceinline__ unsigned short f2bf_rn(float v) {
    __hip_bfloat16 h = __float2bfloat16(v);
    return *reinterpret_cast<unsigned short*>(&h);
}

// ---------------------------------------------------------------------------
// Transpose x[t][c][p] f32 -> xt[t][p][64c] bf16; also copy center frame to out.
// ---------------------------------------------------------------------------
__global__ __launch_bounds__(256) void xprep_kernel(
    const float* __restrict__ x, unsigned short* __restrict__ xt,
    float* __restrict__ out)
{
    const int t = blockIdx.y;
    const int p0 = blockIdx.x * 64;
    const int tid = threadIdx.x;
    __shared__ unsigned short tile[64][72];
    const float* in = x + (size_t)t * PLN;
    const bool isC = (t == 2);
    for (int idx = tid; idx < 4096; idx += 256) {
        int c = idx >> 6, p = idx & 63;
        float v = in[(size_t)c * HWN + p0 + p];
        tile[p][c] = f2bf(v);
        if (isC) out[(size_t)2 * PLN + (size_t)c * HWN + p0 + p] = v;
    }
    __syncthreads();
    unsigned short* xo = xt + ((size_t)t * HWN + p0) * 64;
    for (int task = tid; task < 512; task += 256) {
        int p = task >> 3, cb = task & 7;
        *reinterpret_cast<bf16x8*>(xo + p * 64 + cb * 8) =
            *reinterpret_cast<const bf16x8*>(&tile[p][cb * 8]);
    }
}

// ---------------------------------------------------------------------------
// Weight reorders to K' = g*72 + k*8 + cg, bf16.
// wbf [64][576]  <- w_dcn;  wcbf[2][144][576] <- w_off (slab0 neig, slab1 ctr)
// ---------------------------------------------------------------------------
__global__ __launch_bounds__(256) void wprep_kernel(
    const float* __restrict__ w_dcn, const float* __restrict__ w_off,
    unsigned short* __restrict__ wbf, unsigned short* __restrict__ wcbf)
{
    int idx = blockIdx.x * 256 + threadIdx.x;
    if (idx < 64 * 576) {
        int o = idx / 576, c = idx % 576;
        int g = c / 72, rem = c % 72, k = rem >> 3, cg = rem & 7;
        wbf[idx] = f2bf(w_dcn[o * 576 + (g * 8 + cg) * 9 + k]);
    } else if (idx < 64 * 576 + 2 * 144 * 576) {
        int i2 = idx - 64 * 576;
        int s = i2 / (144 * 576);
        int o = (i2 / 576) % 144;
        int kk = i2 % 576;
        int g = kk / 72, rem = kk % 72, k = rem >> 3, cg = rem & 7;
        wcbf[i2] = f2bf(w_off[(size_t)o * 1152
                              + (size_t)(s * 64 + g * 8 + cg) * 9 + k]);
    }
}

// ---------------------------------------------------------------------------
// Offset conv, LDS-free implicit GEMM. Wave = (f, px-tile, o-triple).
// K = 1152 (neighbor slab + center slab), 36 MFMA steps, 3 o-tiles/wave.
// B-fragment per lane: masked shifted 16B read from xt. Writes ofs[f].
// ---------------------------------------------------------------------------
__global__ __launch_bounds__(256, 4) void conv_mfma_kernel(
    const unsigned short* __restrict__ xt,
    const unsigned short* __restrict__ wcbf,
    const float* __restrict__ b_off,
    float* __restrict__ ofs)
{
    const int gw = blockIdx.x * 4 + (threadIdx.x >> 6);
    const int l  = threadIdx.x & 63;
    const int ot3 = gw % 3;             // o-triple: oc [ot3*48, ot3*48+48)
    const int pt  = (gw / 3) % 576;
    const int f   = gw / 1728;
    const int t   = f < 2 ? f : f + 1;
    const int lr = l & 15, lg = l >> 4;
    const int px = pt * 16 + lr;
    const int y = px / 96, xx = px - y * 96;

    const int ro0 = (y > 0 ? y - 1 : 0) * 96;
    const int ro1 = y * 96;
    const int ro2 = (y < 95 ? y + 1 : 95) * 96;
    const bool vr0 = y > 0, vr2 = y < 95;
    const int co0 = xx > 0 ? xx - 1 : 0;
    const int co2 = xx < 95 ? xx + 1 : 95;
    const bool vc0 = xx > 0, vc2 = xx < 95;

    const bf16x8 bz = {0, 0, 0, 0, 0, 0, 0, 0};
    f32x4 acc0 = {0,0,0,0}, acc1 = {0,0,0,0}, acc2 = {0,0,0,0};
    const int arow = ot3 * 48 + lr;

    for (int hf = 0; hf < 2; ++hf) {
        const unsigned short* xp = xt + (size_t)(hf == 0 ? t : 2) * HWN * 64;
        const unsigned short* wp = wcbf + (size_t)hf * 144 * 576
                                   + (size_t)arow * 576 + lg * 8;
        #pragma unroll
        for (int ss = 0; ss < 18; ++ss) {
            const int j = 4 * ss + lg;
            const int gb = (4 * ss) / 9;                 // compile-time
            const int g = gb + ((j >= 9 * (gb + 1)) ? 1 : 0);
            const int k = j - 9 * g;
            const int r = (k >= 3) + (k >= 6);
            const int d = k - 3 * r;
            const int ro = r == 0 ? ro0 : (r == 1 ? ro1 : ro2);
            const bool vr = r == 0 ? vr0 : (r == 1 ? true : vr2);
            const int co = d == 0 ? co0 : (d == 1 ? xx : co2);
            const bool vc = d == 0 ? vc0 : (d == 1 ? true : vc2);
            bf16x8 b = *reinterpret_cast<const bf16x8*>(
                xp + (size_t)(ro + co) * 64 + g * 8);
            b = (vr && vc) ? b : bz;
            bf16x8 a0 = *reinterpret_cast<const bf16x8*>(wp + ss * 32);
            bf16x8 a1 = *reinterpret_cast<const bf16x8*>(wp + 16 * 576 + ss * 32);
            bf16x8 a2 = *reinterpret_cast<const bf16x8*>(wp + 32 * 576 + ss * 32);
            acc0 = __builtin_amdgcn_mfma_f32_16x16x32_bf16(a0, b, acc0, 0, 0, 0);
            acc1 = __builtin_amdgcn_mfma_f32_16x16x32_bf16(a1, b, acc1, 0, 0, 0);
            acc2 = __builtin_amdgcn_mfma_f32_16x16x32_bf16(a2, b, acc2, 0, 0, 0);
        }
    }

    float* of = ofs + (size_t)f * 144 * HWN + px;
    #pragma unroll
    for (int r = 0; r < 4; ++r) {
        const int o0 = ot3 * 48 + lg * 4 + r;     // C/D: row=(lane>>4)*4+r, col=lr
        of[(size_t)(o0)      * HWN] = acc0[r] + b_off[o0];
        of[(size_t)(o0 + 16) * HWN] = acc1[r] + b_off[o0 + 16];
        of[(size_t)(o0 + 32) * HWN] = acc2[r] + b_off[o0 + 32];
    }
}

// ---------------------------------------------------------------------------
// Deformable sampling + projection, LDS-free. Wave = (f, px-tile, o-half).
// Each lane bilinearly samples its own B fragment (8 ch, 16B corner loads
// from xt), 18 MFMA steps x 2 o-tiles. Writes out[t].
// ---------------------------------------------------------------------------
__global__ __launch_bounds__(256, 4) void deform_kernel(
    const unsigned short* __restrict__ xt,
    const float* __restrict__ ofs,
    const unsigned short* __restrict__ wbf,
    const float* __restrict__ b_dcn,
    float* __restrict__ out)
{
    const int gw = blockIdx.x * 4 + (threadIdx.x >> 6);
    const int l  = threadIdx.x & 63;
    const int oh = gw & 1;              // o-half: oc [oh*32, oh*32+32)
    const int pt = (gw >> 1) % 576;
    const int f  = gw / 1152;
    const int t  = f < 2 ? f : f + 1;
    const int lr = l & 15, lg = l >> 4;
    const int px = pt * 16 + lr;
    const int y = px / 96, xx = px - y * 96;
    const unsigned short* xf = xt + (size_t)t * HWN * 64;
    const float* ofp = ofs + (size_t)f * 144 * HWN + px;
    const unsigned short* wr0 = wbf + (size_t)(oh * 32 + lr) * 576 + lg * 8;

    f32x4 accA = {0,0,0,0}, accB = {0,0,0,0};
    #pragma unroll
    for (int ss = 0; ss < 18; ++ss) {
        const int j = 4 * ss + lg;
        const int gb = (4 * ss) / 9;                 // compile-time
        const int g = gb + ((j >= 9 * (gb + 1)) ? 1 : 0);
        const int k = j - 9 * g;
        const int r = (k >= 3) + (k >= 6);
        const int d = k - 3 * r;
        const float dy = ofp[(size_t)(g * 18 + 2 * k) * HWN];
        const float dx = ofp[(size_t)(g * 18 + 2 * k + 1) * HWN];
        const float ys = (float)(y + r - 1) + dy;
        const float xs = (float)(xx + d - 1) + dx;
        const float y0f = floorf(ys), x0f = floorf(xs);
        const float wy = ys - y0f, wx = xs - x0f;
        const int y0 = (int)y0f, x0 = (int)x0f;
        const int y1 = y0 + 1, x1 = x0 + 1;
        const bool vy0 = (y0 >= 0) & (y0 < 96);
        const bool vy1 = (y1 >= 0) & (y1 < 96);
        const bool vx0 = (x0 >= 0) & (x0 < 96);
        const bool vx1 = (x1 >= 0) & (x1 < 96);
        const int yc0 = min(max(y0, 0), 95), yc1 = min(max(y1, 0), 95);
        const int xc0 = min(max(x0, 0), 95), xc1 = min(max(x1, 0), 95);
        const float w00 = (vy0 & vx0) ? (1.f - wy) * (1.f - wx) : 0.f;
        const float w01 = (vy0 & vx1) ? (1.f - wy) * wx : 0.f;
        const float w10 = (vy1 & vx0) ? wy * (1.f - wx) : 0.f;
        const float w11 = (vy1 & vx1) ? wy * wx : 0.f;
        const unsigned short* base = xf + g * 8;
        bf16x8 c00 = *reinterpret_cast<const bf16x8*>(base + (size_t)(yc0 * 96 + xc0) * 64);
        bf16x8 c01 = *reinterpret_cast<const bf16x8*>(base + (size_t)(yc0 * 96 + xc1) * 64);
        bf16x8 c10 = *reinterpret_cast<const bf16x8*>(base + (size_t)(yc1 * 96 + xc0) * 64);
        bf16x8 c11 = *reinterpret_cast<const bf16x8*>(base + (size_t)(yc1 * 96 + xc1) * 64);
        bf16x8 b;
        #pragma unroll
        for (int ch = 0; ch < 8; ++ch) {
            float v = w00 * bf2f((unsigned short)c00[ch])
                    + w01 * bf2f((unsigned short)c01[ch])
                    + w10 * bf2f((unsigned short)c10[ch])
                    + w11 * bf2f((unsigned short)c11[ch]);
            b[ch] = (short)f2bf_rn(v);
        }
        bf16x8 a0 = *reinterpret_cast<const bf16x8*>(wr0 + ss * 32);
        bf16x8 a1 = *reinterpret_cast<const bf16x8*>(wr0 + 16 * 576 + ss * 32);
        accA = __builtin_amdgcn_mfma_f32_16x16x32_bf16(a0, b, accA, 0, 0, 0);
        accB = __builtin_amdgcn_mfma_f32_16x16x32_bf16(a1, b, accB, 0, 0, 0);
    }

    float* op = out + (size_t)t * PLN + px;
    #pragma unroll
    for (int r = 0; r < 4; ++r) {
        const int o0 = oh * 32 + lg * 4 + r;      // C/D: row=(lane>>4)*4+r, col=lr
        op[(size_t)o0 * HWN]        = accA[r] + b_dcn[o0];
        op[(size_t)(o0 + 16) * HWN] = accB[r] + b_dcn[o0 + 16];
    }
}

extern "C" void kernel_launch(void* const* d_in, const int* in_sizes, int n_in,
                              void* d_out, int out_size, void* d_ws, size_t ws_size,
                              hipStream_t stream) {
    const float* x     = (const float*)d_in[0];
    const float* w_off = (const float*)d_in[1];
    const float* b_off = (const float*)d_in[2];
    const float* w_dcn = (const float*)d_in[3];
    const float* b_dcn = (const float*)d_in[4];
    float* out = (float*)d_out;

    float* ofs          = (float*)d_ws;                        // [4][144][9216] f32, 21.2 MB
    unsigned short* xt  = (unsigned short*)(ofs + (size_t)4 * 144 * HWN); // [5][9216][64] bf16, 5.9 MB
    unsigned short* wbf = xt + (size_t)5 * HWN * 64;           // [64][576] bf16
    unsigned short* wcbf = wbf + 64 * 576;                     // [2][144][576] bf16
    // ws total ~27.6 MB

    // feat transpose to bf16 [pix][ch] + center-frame passthrough
    xprep_kernel<<<dim3(144, 5), 256, 0, stream>>>(x, xt, out);

    // weight reorders
    wprep_kernel<<<792, 256, 0, stream>>>(w_dcn, w_off, wbf, wcbf);

    // offset conv (center+neighbor merged), writes ofs for 4 frames
    conv_mfma_kernel<<<1728, 256, 0, stream>>>(xt, wcbf, b_off, ofs);

    // deformable sampling + projection
    deform_kernel<<<1152, 256, 0, stream>>>(xt, ofs, wbf, b_dcn, out);
}

// Round 8
// 119.154 us; speedup vs baseline: 1.7190x; 1.7190x over previous
//
#include <hip/hip_runtime.h>
#include <hip/hip_bf16.h>

#define HWN 9216              // 96*96
#define PLN (64 * HWN)        // one frame's feature plane (C=64)
#define SLDE 584              // im2col LDS row stride (bf16 elems); 584*2=1168B == 16 mod 128 -> conflict-free b128

typedef __attribute__((ext_vector_type(8))) short bf16x8;
typedef __attribute__((ext_vector_type(4))) float f32x4;

__device__ __forceinline__ unsigned short f2bf(float v) {
    union { float f; unsigned u; } cv; cv.f = v;
    unsigned u = cv.u;
    u += 0x7fffu + ((u >> 16) & 1u);   // round-to-nearest-even
    return (unsigned short)(u >> 16);
}
__device__ __forceinline__ float bf2f(unsigned short b) {
    union { unsigned u; float f; } cv; cv.u = ((unsigned)b) << 16;
    return cv.f;
}

// ---------------------------------------------------------------------------
// Transpose x[t][c][p] f32 -> xt[t][p][64c] bf16; also copy center frame to out.
// ---------------------------------------------------------------------------
__global__ __launch_bounds__(256) void xprep_kernel(
    const float* __restrict__ x, unsigned short* __restrict__ xt,
    float* __restrict__ out)
{
    const int t = blockIdx.y;
    const int p0 = blockIdx.x * 64;
    const int tid = threadIdx.x;
    __shared__ unsigned short tile[64][72];
    const float* in = x + (size_t)t * PLN;
    const bool isC = (t == 2);
    for (int idx = tid; idx < 4096; idx += 256) {
        int c = idx >> 6, p = idx & 63;
        float v = in[(size_t)c * HWN + p0 + p];
        tile[p][c] = f2bf(v);
        if (isC) out[(size_t)2 * PLN + (size_t)c * HWN + p0 + p] = v;
    }
    __syncthreads();
    unsigned short* xo = xt + ((size_t)t * HWN + p0) * 64;
    for (int task = tid; task < 512; task += 256) {
        int p = task >> 3, cb = task & 7;
        *reinterpret_cast<bf16x8*>(xo + p * 64 + cb * 8) =
            *reinterpret_cast<const bf16x8*>(&tile[p][cb * 8]);
    }
}

// ---------------------------------------------------------------------------
// Weight reorders to K' = g*72 + k*8 + cg, bf16.
// wbf [64][576] <- w_dcn;  wcbf[2][144][576] <- w_off (slab0 neig, slab1 ctr)
// ---------------------------------------------------------------------------
__global__ __launch_bounds__(256) void wprep_kernel(
    const float* __restrict__ w_dcn, const float* __restrict__ w_off,
    unsigned short* __restrict__ wbf, unsigned short* __restrict__ wcbf)
{
    int idx = blockIdx.x * 256 + threadIdx.x;
    if (idx < 64 * 576) {
        int o = idx / 576, c = idx % 576;
        int g = c / 72, rem = c % 72, k = rem >> 3, cg = rem & 7;
        wbf[idx] = f2bf(w_dcn[o * 576 + (g * 8 + cg) * 9 + k]);
    } else if (idx < 64 * 576 + 2 * 144 * 576) {
        int i2 = idx - 64 * 576;
        int s = i2 / (144 * 576);
        int o = (i2 / 576) % 144;
        int kk = i2 % 576;
        int g = kk / 72, rem = kk % 72, k = rem >> 3, cg = rem & 7;
        wcbf[i2] = f2bf(w_off[(size_t)o * 1152
                              + (size_t)(s * 64 + g * 8 + cg) * 9 + k]);
    }
}

// ---------------------------------------------------------------------------
// Offset conv v3: LDS im2col + MFMA, both K-slabs merged (K=1152).
// Block: 576 thr (9 waves), 64-px tile, one frame f.
// hf=0: neighbor frame slab; hf=1: center frame slab. acc accumulates.
// Phase A (8 waves): im2col [64px][576K'] bf16 into LDS (9 x 16B vec loads).
// Phase B (9 waves): wave w = o-tile (16 oc), A-frags in regs, 4 px-subtiles.
// ---------------------------------------------------------------------------
__global__ __launch_bounds__(576, 2) void conv_mfma_kernel(
    const unsigned short* __restrict__ xt,
    const unsigned short* __restrict__ wcbf,
    const float* __restrict__ b_off,
    float* __restrict__ ofs)
{
    const int f = blockIdx.y;
    const int t = f < 2 ? f : f + 1;
    const int p0 = blockIdx.x * 64;
    const int tid = threadIdx.x;
    const int w = tid >> 6, l = tid & 63;
    const int lr = l & 15, lg = l >> 4;

    __shared__ unsigned short smp[64 * SLDE];

    f32x4 acc[4] = {{0,0,0,0},{0,0,0,0},{0,0,0,0},{0,0,0,0}};

    #pragma unroll
    for (int hf = 0; hf < 2; ++hf) {
        if (hf) __syncthreads();        // all reads of smp done before restage
        // ---- stage im2col slab ----
        if (tid < 512) {
            const int g = tid >> 6, pl = tid & 63;
            const int p = p0 + pl;
            const int y = p / 96, xx = p - y * 96;
            const unsigned short* xp =
                xt + (size_t)(hf ? 2 : t) * HWN * 64 + g * 8;
            unsigned short* srow = smp + pl * SLDE + g * 72;
            const bf16x8 bz = {0,0,0,0,0,0,0,0};
            #pragma unroll
            for (int k = 0; k < 9; ++k) {
                const int r = k / 3, d = k - 3 * (k / 3);
                const int yy = y + r - 1, xw = xx + d - 1;
                const bool valid = (yy >= 0) & (yy < 96) & (xw >= 0) & (xw < 96);
                const int lin = min(max(yy, 0), 95) * 96 + min(max(xw, 0), 95);
                bf16x8 v = *reinterpret_cast<const bf16x8*>(xp + (size_t)lin * 64);
                if (!valid) v = bz;
                *reinterpret_cast<bf16x8*>(srow + k * 8) = v;
            }
        }
        __syncthreads();
        // ---- A-frag preload (16B global loads, L2-hot) ----
        const unsigned short* wp = wcbf + (size_t)hf * 144 * 576
                                   + (size_t)(w * 16 + lr) * 576 + lg * 8;
        bf16x8 afr[18];
        #pragma unroll
        for (int ss = 0; ss < 18; ++ss)
            afr[ss] = *reinterpret_cast<const bf16x8*>(wp + ss * 32);
        // ---- MFMA: 4 px-subtiles x 18 K-steps ----
        #pragma unroll
        for (int pt = 0; pt < 4; ++pt) {
            const unsigned short* brow = smp + (pt * 16 + lr) * SLDE + lg * 8;
            #pragma unroll
            for (int ss = 0; ss < 18; ++ss) {
                bf16x8 b = *reinterpret_cast<const bf16x8*>(brow + ss * 32);
                acc[pt] = __builtin_amdgcn_mfma_f32_16x16x32_bf16(afr[ss], b, acc[pt], 0, 0, 0);
            }
        }
    }

    float* of = ofs + (size_t)f * 144 * HWN;
    #pragma unroll
    for (int pt = 0; pt < 4; ++pt) {
        const int px = p0 + pt * 16 + lr;
        #pragma unroll
        for (int r = 0; r < 4; ++r) {
            const int o = w * 16 + lg * 4 + r;   // C/D: row=(lane>>4)*4+r, col=lane&15
            of[(size_t)o * HWN + px] = acc[pt][r] + b_off[o];
        }
    }
}

// ---------------------------------------------------------------------------
// Deform v2: LDS-free, wave = (f, px-tile) computes ALL 64 oc (4 o-tiles).
// All 36 offset scalars preloaded; corner/weight loads pipelined depth-2.
// ---------------------------------------------------------------------------
struct Slot {
    bf16x8 c00, c01, c10, c11;
    bf16x8 a0, a1, a2, a3;
    float w00, w01, w10, w11;
};

__global__ __launch_bounds__(256, 3) void deform_kernel(
    const unsigned short* __restrict__ xt,
    const float* __restrict__ ofs,
    const unsigned short* __restrict__ wbf,
    const float* __restrict__ b_dcn,
    float* __restrict__ out)
{
    const int gw = blockIdx.x * 4 + (threadIdx.x >> 6);
    const int l  = threadIdx.x & 63;
    const int pt = gw % 576;
    const int f  = gw / 576;
    const int t  = f < 2 ? f : f + 1;
    const int lr = l & 15, lg = l >> 4;
    const int px = pt * 16 + lr;
    const int y = px / 96, xx = px - y * 96;
    const unsigned short* xf = xt + (size_t)t * HWN * 64;
    const float* ofp = ofs + (size_t)f * 144 * HWN + px;

    // preload all offsets: plane index g*18+2k == 2j, j = 4*ss+lg
    float dy[18], dx[18];
    #pragma unroll
    for (int ss = 0; ss < 18; ++ss) {
        dy[ss] = ofp[(size_t)(8 * ss + 2 * lg) * HWN];
        dx[ss] = ofp[(size_t)(8 * ss + 2 * lg + 1) * HWN];
    }

    f32x4 acc[4] = {{0,0,0,0},{0,0,0,0},{0,0,0,0},{0,0,0,0}};

    auto stage = [&](int ss, Slot& S) {
        const int j = 4 * ss + lg;
        const int g = j / 9, k = j - 9 * g;
        const int r = k / 3, d = k - 3 * (k / 3);
        const float ys = (float)(y + r - 1) + dy[ss];
        const float xs = (float)(xx + d - 1) + dx[ss];
        const float y0f = floorf(ys), x0f = floorf(xs);
        const float wy = ys - y0f, wx = xs - x0f;
        const int y0 = (int)y0f, x0 = (int)x0f;
        const int y1 = y0 + 1, x1 = x0 + 1;
        const bool vy0 = (y0 >= 0) & (y0 < 96);
        const bool vy1 = (y1 >= 0) & (y1 < 96);
        const bool vx0 = (x0 >= 0) & (x0 < 96);
        const bool vx1 = (x1 >= 0) & (x1 < 96);
        const int yc0 = min(max(y0, 0), 95), yc1 = min(max(y1, 0), 95);
        const int xc0 = min(max(x0, 0), 95), xc1 = min(max(x1, 0), 95);
        S.w00 = (vy0 & vx0) ? (1.f - wy) * (1.f - wx) : 0.f;
        S.w01 = (vy0 & vx1) ? (1.f - wy) * wx : 0.f;
        S.w10 = (vy1 & vx0) ? wy * (1.f - wx) : 0.f;
        S.w11 = (vy1 & vx1) ? wy * wx : 0.f;
        const unsigned short* base = xf + g * 8;
        S.c00 = *reinterpret_cast<const bf16x8*>(base + (size_t)(yc0 * 96 + xc0) * 64);
        S.c01 = *reinterpret_cast<const bf16x8*>(base + (size_t)(yc0 * 96 + xc1) * 64);
        S.c10 = *reinterpret_cast<const bf16x8*>(base + (size_t)(yc1 * 96 + xc0) * 64);
        S.c11 = *reinterpret_cast<const bf16x8*>(base + (size_t)(yc1 * 96 + xc1) * 64);
        const unsigned short* wr = wbf + (size_t)lr * 576 + ss * 32 + lg * 8;
        S.a0 = *reinterpret_cast<const bf16x8*>(wr);
        S.a1 = *reinterpret_cast<const bf16x8*>(wr + 16 * 576);
        S.a2 = *reinterpret_cast<const bf16x8*>(wr + 32 * 576);
        S.a3 = *reinterpret_cast<const bf16x8*>(wr + 48 * 576);
    };
    auto compute = [&](const Slot& S) {
        bf16x8 b;
        #pragma unroll
        for (int ch = 0; ch < 8; ++ch) {
            float v = S.w00 * bf2f((unsigned short)S.c00[ch]);
            v = fmaf(S.w01, bf2f((unsigned short)S.c01[ch]), v);
            v = fmaf(S.w10, bf2f((unsigned short)S.c10[ch]), v);
            v = fmaf(S.w11, bf2f((unsigned short)S.c11[ch]), v);
            b[ch] = (short)f2bf(v);
        }
        acc[0] = __builtin_amdgcn_mfma_f32_16x16x32_bf16(S.a0, b, acc[0], 0, 0, 0);
        acc[1] = __builtin_amdgcn_mfma_f32_16x16x32_bf16(S.a1, b, acc[1], 0, 0, 0);
        acc[2] = __builtin_amdgcn_mfma_f32_16x16x32_bf16(S.a2, b, acc[2], 0, 0, 0);
        acc[3] = __builtin_amdgcn_mfma_f32_16x16x32_bf16(S.a3, b, acc[3], 0, 0, 0);
    };

    Slot sA, sB;
    stage(0, sA);
    #pragma unroll
    for (int sp = 0; sp < 9; ++sp) {
        stage(2 * sp + 1, sB);          // prefetch odd step
        compute(sA);                    // consume even step
        if (sp < 8) stage(2 * sp + 2, sA);  // prefetch next even
        compute(sB);                    // consume odd step
    }

    float* op = out + (size_t)t * PLN + px;
    #pragma unroll
    for (int ot = 0; ot < 4; ++ot) {
        #pragma unroll
        for (int r = 0; r < 4; ++r) {
            const int o = ot * 16 + lg * 4 + r;   // C/D: row=(lane>>4)*4+r, col=lane&15
            op[(size_t)o * HWN] = acc[ot][r] + b_dcn[o];
        }
    }
}

extern "C" void kernel_launch(void* const* d_in, const int* in_sizes, int n_in,
                              void* d_out, int out_size, void* d_ws, size_t ws_size,
                              hipStream_t stream) {
    const float* x     = (const float*)d_in[0];
    const float* w_off = (const float*)d_in[1];
    const float* b_off = (const float*)d_in[2];
    const float* w_dcn = (const float*)d_in[3];
    const float* b_dcn = (const float*)d_in[4];
    float* out = (float*)d_out;

    float* ofs          = (float*)d_ws;                        // [4][144][9216] f32, 21.2 MB
    unsigned short* xt  = (unsigned short*)(ofs + (size_t)4 * 144 * HWN); // [5][9216][64] bf16, 5.9 MB
    unsigned short* wbf = xt + (size_t)5 * HWN * 64;           // [64][576] bf16
    unsigned short* wcbf = wbf + (size_t)64 * 576;             // [2][144][576] bf16
    // ws total ~27.6 MB

    // feat transpose to bf16 [pix][ch] + center-frame passthrough
    xprep_kernel<<<dim3(144, 5), 256, 0, stream>>>(x, xt, out);

    // weight reorders
    wprep_kernel<<<792, 256, 0, stream>>>(w_dcn, w_off, wbf, wcbf);

    // offset conv (both slabs fused), writes ofs for 4 frames
    conv_mfma_kernel<<<dim3(144, 4), 576, 0, stream>>>(xt, wcbf, b_off, ofs);

    // deformable sampling + projection (all 64 oc per wave, depth-2 pipeline)
    deform_kernel<<<576, 256, 0, stream>>>(xt, ofs, wbf, b_dcn, out);
}

// Round 9
// 106.882 us; speedup vs baseline: 1.9164x; 1.1148x over previous
//
#include <hip/hip_runtime.h>
#include <hip/hip_bf16.h>

#define HWN 9216              // 96*96
#define PLN (64 * HWN)        // one frame's feature plane (C=64)
#define SLDE 584              // LDS row stride (bf16); 292 dwords == 4*73 -> conflict-free b128

typedef __attribute__((ext_vector_type(8))) short bf16x8;
typedef __attribute__((ext_vector_type(4))) float f32x4;

__device__ __forceinline__ unsigned short f2bf(float v) {
    union { float f; unsigned u; } cv; cv.f = v;
    unsigned u = cv.u;
    u += 0x7fffu + ((u >> 16) & 1u);   // round-to-nearest-even
    return (unsigned short)(u >> 16);
}
__device__ __forceinline__ float bf2f(unsigned short b) {
    union { unsigned u; float f; } cv; cv.u = ((unsigned)b) << 16;
    return cv.f;
}

// ---------------------------------------------------------------------------
// Transpose x[t][c][p] f32 -> xt[t][p][64c] bf16; also copy center frame to out.
// ---------------------------------------------------------------------------
__global__ __launch_bounds__(256) void xprep_kernel(
    const float* __restrict__ x, unsigned short* __restrict__ xt,
    float* __restrict__ out)
{
    const int t = blockIdx.y;
    const int p0 = blockIdx.x * 64;
    const int tid = threadIdx.x;
    __shared__ unsigned short tile[64][72];
    const float* in = x + (size_t)t * PLN;
    const bool isC = (t == 2);
    for (int idx = tid; idx < 4096; idx += 256) {
        int c = idx >> 6, p = idx & 63;
        float v = in[(size_t)c * HWN + p0 + p];
        tile[p][c] = f2bf(v);
        if (isC) out[(size_t)2 * PLN + (size_t)c * HWN + p0 + p] = v;
    }
    __syncthreads();
    unsigned short* xo = xt + ((size_t)t * HWN + p0) * 64;
    for (int task = tid; task < 512; task += 256) {
        int p = task >> 3, cb = task & 7;
        *reinterpret_cast<bf16x8*>(xo + p * 64 + cb * 8) =
            *reinterpret_cast<const bf16x8*>(&tile[p][cb * 8]);
    }
}

// ---------------------------------------------------------------------------
// Weight reorders to K' = g*72 + k*8 + cg, bf16.
// wbf [64][576] <- w_dcn;  wcbf[2][144][576] <- w_off (slab0 neig, slab1 ctr)
// ---------------------------------------------------------------------------
__global__ __launch_bounds__(256) void wprep_kernel(
    const float* __restrict__ w_dcn, const float* __restrict__ w_off,
    unsigned short* __restrict__ wbf, unsigned short* __restrict__ wcbf)
{
    int idx = blockIdx.x * 256 + threadIdx.x;
    if (idx < 64 * 576) {
        int o = idx / 576, c = idx % 576;
        int g = c / 72, rem = c % 72, k = rem >> 3, cg = rem & 7;
        wbf[idx] = f2bf(w_dcn[o * 576 + (g * 8 + cg) * 9 + k]);
    } else if (idx < 64 * 576 + 2 * 144 * 576) {
        int i2 = idx - 64 * 576;
        int s = i2 / (144 * 576);
        int o = (i2 / 576) % 144;
        int kk = i2 % 576;
        int g = kk / 72, rem = kk % 72, k = rem >> 3, cg = rem & 7;
        wcbf[i2] = f2bf(w_off[(size_t)o * 1152
                              + (size_t)(s * 64 + g * 8 + cg) * 9 + k]);
    }
}

// ---------------------------------------------------------------------------
// Offset conv: LDS im2col + MFMA, both K-slabs merged (K=1152). Unchanged
// from round 8 (~fine). 576 thr (9 waves), 64-px tile, one frame.
// ---------------------------------------------------------------------------
__global__ __launch_bounds__(576, 2) void conv_mfma_kernel(
    const unsigned short* __restrict__ xt,
    const unsigned short* __restrict__ wcbf,
    const float* __restrict__ b_off,
    float* __restrict__ ofs)
{
    const int f = blockIdx.y;
    const int t = f < 2 ? f : f + 1;
    const int p0 = blockIdx.x * 64;
    const int tid = threadIdx.x;
    const int w = tid >> 6, l = tid & 63;
    const int lr = l & 15, lg = l >> 4;

    __shared__ unsigned short smp[64 * SLDE];

    f32x4 acc[4] = {{0,0,0,0},{0,0,0,0},{0,0,0,0},{0,0,0,0}};

    #pragma unroll
    for (int hf = 0; hf < 2; ++hf) {
        if (hf) __syncthreads();        // all reads of smp done before restage
        if (tid < 512) {
            const int g = tid >> 6, pl = tid & 63;
            const int p = p0 + pl;
            const int y = p / 96, xx = p - y * 96;
            const unsigned short* xp =
                xt + (size_t)(hf ? 2 : t) * HWN * 64 + g * 8;
            unsigned short* srow = smp + pl * SLDE + g * 72;
            const bf16x8 bz = {0,0,0,0,0,0,0,0};
            #pragma unroll
            for (int k = 0; k < 9; ++k) {
                const int r = k / 3, d = k - 3 * (k / 3);
                const int yy = y + r - 1, xw = xx + d - 1;
                const bool valid = (yy >= 0) & (yy < 96) & (xw >= 0) & (xw < 96);
                const int lin = min(max(yy, 0), 95) * 96 + min(max(xw, 0), 95);
                bf16x8 v = *reinterpret_cast<const bf16x8*>(xp + (size_t)lin * 64);
                if (!valid) v = bz;
                *reinterpret_cast<bf16x8*>(srow + k * 8) = v;
            }
        }
        __syncthreads();
        const unsigned short* wp = wcbf + (size_t)hf * 144 * 576
                                   + (size_t)(w * 16 + lr) * 576 + lg * 8;
        bf16x8 afr[18];
        #pragma unroll
        for (int ss = 0; ss < 18; ++ss)
            afr[ss] = *reinterpret_cast<const bf16x8*>(wp + ss * 32);
        #pragma unroll
        for (int pt = 0; pt < 4; ++pt) {
            const unsigned short* brow = smp + (pt * 16 + lr) * SLDE + lg * 8;
            #pragma unroll
            for (int ss = 0; ss < 18; ++ss) {
                bf16x8 b = *reinterpret_cast<const bf16x8*>(brow + ss * 32);
                acc[pt] = __builtin_amdgcn_mfma_f32_16x16x32_bf16(afr[ss], b, acc[pt], 0, 0, 0);
            }
        }
    }

    float* of = ofs + (size_t)f * 144 * HWN;
    #pragma unroll
    for (int pt = 0; pt < 4; ++pt) {
        const int px = p0 + pt * 16 + lr;
        #pragma unroll
        for (int r = 0; r < 4; ++r) {
            const int o = w * 16 + lg * 4 + r;   // C/D: row=(lane>>4)*4+r, col=lane&15
            of[(size_t)o * HWN + px] = acc[pt][r] + b_off[o];
        }
    }
}

// ---------------------------------------------------------------------------
// Deform v3: LDS-staged sampling (max MLP) + MFMA projection.
// Block: 512 thr (8 waves), 64-px tile, one frame.
// Phase 1: thread = (g, px): 36 independent 16B gathers -> lerp -> LDS row.
// Phase 2: wave w: o-tile (w&3), px-subtiles (w>>2)*16 and +32 (round-3 map).
// ---------------------------------------------------------------------------
__global__ __launch_bounds__(512, 2) void deform_kernel(
    const unsigned short* __restrict__ xt,
    const float* __restrict__ ofs,
    const unsigned short* __restrict__ wbf,
    const float* __restrict__ b_dcn,
    float* __restrict__ out)
{
    const int f = blockIdx.y;
    const int t = f < 2 ? f : f + 1;
    const int p0 = blockIdx.x * 64;
    const int tid = threadIdx.x;

    __shared__ unsigned short smp[64 * SLDE];   // [pix][K'] bf16, K' = g*72+k*8+cg

    // ---- phase 1: sampling, one (g, pixel) task per thread ----
    {
        const int g = tid >> 6, pl = tid & 63;
        const int p = p0 + pl;
        const int y = p / 96, xx = p - y * 96;
        const unsigned short* xf = xt + (size_t)t * HWN * 64 + g * 8;
        const float* ob = ofs + (size_t)f * 144 * HWN + (size_t)g * 18 * HWN + p;
        float dy[9], dx[9];
        #pragma unroll
        for (int k = 0; k < 9; ++k) {           // 18 coalesced scalar loads
            dy[k] = ob[(size_t)(2 * k) * HWN];
            dx[k] = ob[(size_t)(2 * k + 1) * HWN];
        }
        unsigned short* srow = smp + pl * SLDE + g * 72;
        #pragma unroll
        for (int k = 0; k < 9; ++k) {
            const int r = k / 3, d = k - 3 * (k / 3);
            const float ys = (float)(y + r - 1) + dy[k];
            const float xs = (float)(xx + d - 1) + dx[k];
            const float y0f = floorf(ys), x0f = floorf(xs);
            const float wy = ys - y0f, wx = xs - x0f;
            const int y0 = (int)y0f, x0 = (int)x0f;
            const int y1 = y0 + 1, x1 = x0 + 1;
            const bool vy0 = (y0 >= 0) & (y0 < 96);
            const bool vy1 = (y1 >= 0) & (y1 < 96);
            const bool vx0 = (x0 >= 0) & (x0 < 96);
            const bool vx1 = (x1 >= 0) & (x1 < 96);
            const int yc0 = min(max(y0, 0), 95), yc1 = min(max(y1, 0), 95);
            const int xc0 = min(max(x0, 0), 95), xc1 = min(max(x1, 0), 95);
            const float w00 = (vy0 & vx0) ? (1.f - wy) * (1.f - wx) : 0.f;
            const float w01 = (vy0 & vx1) ? (1.f - wy) * wx : 0.f;
            const float w10 = (vy1 & vx0) ? wy * (1.f - wx) : 0.f;
            const float w11 = (vy1 & vx1) ? wy * wx : 0.f;
            bf16x8 c00 = *reinterpret_cast<const bf16x8*>(xf + (size_t)(yc0 * 96 + xc0) * 64);
            bf16x8 c01 = *reinterpret_cast<const bf16x8*>(xf + (size_t)(yc0 * 96 + xc1) * 64);
            bf16x8 c10 = *reinterpret_cast<const bf16x8*>(xf + (size_t)(yc1 * 96 + xc0) * 64);
            bf16x8 c11 = *reinterpret_cast<const bf16x8*>(xf + (size_t)(yc1 * 96 + xc1) * 64);
            bf16x8 pk;
            #pragma unroll
            for (int ch = 0; ch < 8; ++ch) {
                float v = w00 * bf2f((unsigned short)c00[ch]);
                v = fmaf(w01, bf2f((unsigned short)c01[ch]), v);
                v = fmaf(w10, bf2f((unsigned short)c10[ch]), v);
                v = fmaf(w11, bf2f((unsigned short)c11[ch]), v);
                pk[ch] = (short)f2bf(v);
            }
            *reinterpret_cast<bf16x8*>(srow + k * 8) = pk;   // 16B aligned
        }
    }
    __syncthreads();

    // ---- phase 2: MFMA. wave w: o-tile (w&3), px-tiles (w>>2)*16 and +32 ----
    const int w = tid >> 6;
    const int l = tid & 63;
    const int o0 = (w & 3) * 16;
    const int pt0 = (w >> 2) * 16;
    const int lr = l & 15, lg = l >> 4;

    bf16x8 afr[18];
    const unsigned short* wrow = wbf + (size_t)(o0 + lr) * 576 + lg * 8;
    #pragma unroll
    for (int s = 0; s < 18; ++s)
        afr[s] = *reinterpret_cast<const bf16x8*>(wrow + s * 32);

    f32x4 acc0 = {0.f, 0.f, 0.f, 0.f}, acc1 = {0.f, 0.f, 0.f, 0.f};
    const unsigned short* brow0 = smp + (pt0 + lr) * SLDE + lg * 8;
    const unsigned short* brow1 = brow0 + 32 * SLDE;
    #pragma unroll
    for (int s = 0; s < 18; ++s) {
        bf16x8 b0 = *reinterpret_cast<const bf16x8*>(brow0 + s * 32);
        bf16x8 b1 = *reinterpret_cast<const bf16x8*>(brow1 + s * 32);
        acc0 = __builtin_amdgcn_mfma_f32_16x16x32_bf16(afr[s], b0, acc0, 0, 0, 0);
        acc1 = __builtin_amdgcn_mfma_f32_16x16x32_bf16(afr[s], b1, acc1, 0, 0, 0);
    }

    float* op = out + (size_t)t * PLN + p0;
    #pragma unroll
    for (int r = 0; r < 4; ++r) {
        const int o = o0 + lg * 4 + r;              // C/D: row=(lane>>4)*4+r
        const float bb = b_dcn[o];
        op[(size_t)o * HWN + pt0 + lr] = acc0[r] + bb;        // col = lane&15
        op[(size_t)o * HWN + pt0 + 32 + lr] = acc1[r] + bb;
    }
}

extern "C" void kernel_launch(void* const* d_in, const int* in_sizes, int n_in,
                              void* d_out, int out_size, void* d_ws, size_t ws_size,
                              hipStream_t stream) {
    const float* x     = (const float*)d_in[0];
    const float* w_off = (const float*)d_in[1];
    const float* b_off = (const float*)d_in[2];
    const float* w_dcn = (const float*)d_in[3];
    const float* b_dcn = (const float*)d_in[4];
    float* out = (float*)d_out;

    float* ofs          = (float*)d_ws;                        // [4][144][9216] f32, 21.2 MB
    unsigned short* xt  = (unsigned short*)(ofs + (size_t)4 * 144 * HWN); // [5][9216][64] bf16, 5.9 MB
    unsigned short* wbf = xt + (size_t)5 * HWN * 64;           // [64][576] bf16
    unsigned short* wcbf = wbf + (size_t)64 * 576;             // [2][144][576] bf16
    // ws total ~27.6 MB

    // feat transpose to bf16 [pix][ch] + center-frame passthrough
    xprep_kernel<<<dim3(144, 5), 256, 0, stream>>>(x, xt, out);

    // weight reorders
    wprep_kernel<<<792, 256, 0, stream>>>(w_dcn, w_off, wbf, wcbf);

    // offset conv (both slabs fused), writes ofs for 4 frames
    conv_mfma_kernel<<<dim3(144, 4), 576, 0, stream>>>(xt, wcbf, b_off, ofs);

    // deformable sampling + projection (LDS-staged sampling, 8 waves)
    deform_kernel<<<dim3(144, 4), 512, 0, stream>>>(xt, ofs, wbf, b_dcn, out);
}

// Round 10
// 106.014 us; speedup vs baseline: 1.9321x; 1.0082x over previous
//
#include <hip/hip_runtime.h>
#include <hip/hip_bf16.h>

#define HWN 9216              // 96*96
#define PLN (64 * HWN)        // one frame's feature plane (C=64)
#define SLDE 584              // LDS row stride (bf16 elems)

typedef __attribute__((ext_vector_type(8))) short bf16x8;
typedef __attribute__((ext_vector_type(4))) float f32x4;

__device__ __forceinline__ unsigned short f2bf(float v) {
    union { float f; unsigned u; } cv; cv.f = v;
    unsigned u = cv.u;
    u += 0x7fffu + ((u >> 16) & 1u);   // round-to-nearest-even
    return (unsigned short)(u >> 16);
}
__device__ __forceinline__ float bf2f(unsigned short b) {
    union { unsigned u; float f; } cv; cv.u = ((unsigned)b) << 16;
    return cv.f;
}

// ---------------------------------------------------------------------------
// y<5 : transpose x[t][c][p] f32 -> xt[t][p][64c] bf16 (+ center copy to out)
// y==5: weight reorders to K' = g*72 + k*8 + cg, bf16:
//       wbf[64][576] <- w_dcn; wcbf[2][144][576] <- w_off (slab0 neig, 1 ctr)
// ---------------------------------------------------------------------------
__global__ __launch_bounds__(256) void xprep_kernel(
    const float* __restrict__ x, const float* __restrict__ w_dcn,
    const float* __restrict__ w_off, unsigned short* __restrict__ xt,
    unsigned short* __restrict__ wbf, unsigned short* __restrict__ wcbf,
    float* __restrict__ out)
{
    const int t = blockIdx.y;
    const int tid = threadIdx.x;
    if (t == 5) {   // weight prep
        for (int idx = blockIdx.x * 256 + tid; idx < 64 * 576 + 2 * 144 * 576;
             idx += 144 * 256) {
            if (idx < 64 * 576) {
                int o = idx / 576, c = idx % 576;
                int g = c / 72, rem = c % 72, k = rem >> 3, cg = rem & 7;
                wbf[idx] = f2bf(w_dcn[o * 576 + (g * 8 + cg) * 9 + k]);
            } else {
                int i2 = idx - 64 * 576;
                int s = i2 / (144 * 576);
                int o = (i2 / 576) % 144;
                int kk = i2 % 576;
                int g = kk / 72, rem = kk % 72, k = rem >> 3, cg = rem & 7;
                wcbf[i2] = f2bf(w_off[(size_t)o * 1152
                                      + (size_t)(s * 64 + g * 8 + cg) * 9 + k]);
            }
        }
        return;
    }
    const int p0 = blockIdx.x * 64;
    __shared__ unsigned short tile[64][72];
    const float* in = x + (size_t)t * PLN;
    const bool isC = (t == 2);
    for (int idx = tid; idx < 4096; idx += 256) {
        int c = idx >> 6, p = idx & 63;
        float v = in[(size_t)c * HWN + p0 + p];
        tile[p][c] = f2bf(v);
        if (isC) out[(size_t)2 * PLN + (size_t)c * HWN + p0 + p] = v;
    }
    __syncthreads();
    unsigned short* xo = xt + ((size_t)t * HWN + p0) * 64;
    for (int task = tid; task < 512; task += 256) {
        int p = task >> 3, cb = task & 7;
        *reinterpret_cast<bf16x8*>(xo + p * 64 + cb * 8) =
            *reinterpret_cast<const bf16x8*>(&tile[p][cb * 8]);
    }
}

// ---------------------------------------------------------------------------
// Offset conv: LDS im2col + MFMA, both K-slabs merged (K=1152).
// 576 thr (9 waves), 32-px tile (LDS 37.4KB -> 3 blocks/CU), one frame.
// Stage: 2304 granule-tasks, 4 per thread. Wave w = 16-oc tile.
// ---------------------------------------------------------------------------
__global__ __launch_bounds__(576, 6) void conv_mfma_kernel(
    const unsigned short* __restrict__ xt,
    const unsigned short* __restrict__ wcbf,
    const float* __restrict__ b_off,
    float* __restrict__ ofs)
{
    const int f = blockIdx.y;
    const int t = f < 2 ? f : f + 1;
    const int p0 = blockIdx.x * 32;
    const int tid = threadIdx.x;
    const int w = tid >> 6, l = tid & 63;
    const int lr = l & 15, lg = l >> 4;

    __shared__ unsigned short smp[32 * SLDE];

    f32x4 acc[2] = {{0,0,0,0},{0,0,0,0}};

    #pragma unroll
    for (int hf = 0; hf < 2; ++hf) {
        if (hf) __syncthreads();        // all reads of smp done before restage
        // ---- stage im2col slab: tasks (k 0..8, g 0..7, pl 0..31) ----
        {
            const unsigned short* xb = xt + (size_t)(hf ? 2 : t) * HWN * 64;
            const bf16x8 bz = {0,0,0,0,0,0,0,0};
            #pragma unroll
            for (int i = 0; i < 4; ++i) {
                const int tsk = tid + i * 576;          // 0..2303
                const int k = tsk >> 8;
                const int rem = tsk & 255;
                const int g = rem >> 5, pl = rem & 31;
                const int p = p0 + pl;
                const int y = p / 96, xx = p - y * 96;
                const int r = k / 3, d = k - 3 * (k / 3);
                const int yy = y + r - 1, xw = xx + d - 1;
                const bool valid = (yy >= 0) & (yy < 96) & (xw >= 0) & (xw < 96);
                const int lin = min(max(yy, 0), 95) * 96 + min(max(xw, 0), 95);
                bf16x8 v = *reinterpret_cast<const bf16x8*>(
                    xb + (size_t)lin * 64 + g * 8);
                if (!valid) v = bz;
                *reinterpret_cast<bf16x8*>(smp + pl * SLDE + g * 72 + k * 8) = v;
            }
        }
        __syncthreads();
        // ---- A-frag preload (L2-hot) + MFMA: 2 px-subtiles x 18 K-steps ----
        const unsigned short* wp = wcbf + (size_t)hf * 144 * 576
                                   + (size_t)(w * 16 + lr) * 576 + lg * 8;
        bf16x8 afr[18];
        #pragma unroll
        for (int ss = 0; ss < 18; ++ss)
            afr[ss] = *reinterpret_cast<const bf16x8*>(wp + ss * 32);
        #pragma unroll
        for (int pt = 0; pt < 2; ++pt) {
            const unsigned short* brow = smp + (pt * 16 + lr) * SLDE + lg * 8;
            #pragma unroll
            for (int ss = 0; ss < 18; ++ss) {
                bf16x8 b = *reinterpret_cast<const bf16x8*>(brow + ss * 32);
                acc[pt] = __builtin_amdgcn_mfma_f32_16x16x32_bf16(afr[ss], b, acc[pt], 0, 0, 0);
            }
        }
    }

    float* of = ofs + (size_t)f * 144 * HWN;
    #pragma unroll
    for (int pt = 0; pt < 2; ++pt) {
        const int px = p0 + pt * 16 + lr;
        #pragma unroll
        for (int r = 0; r < 4; ++r) {
            const int o = w * 16 + lg * 4 + r;   // C/D: row=(lane>>4)*4+r, col=lane&15
            of[(size_t)o * HWN + px] = acc[pt][r] + b_off[o];
        }
    }
}

// ---------------------------------------------------------------------------
// Deform: LDS-staged sampling + MFMA projection. 256 thr (4 waves),
// 32-px tile (LDS 37.4KB -> 4 blocks/CU), one frame.
// Phase 1: thread = (g 0..7, pl 0..31): 36 16B gathers -> lerp -> LDS row.
// Phase 2: wave w = 16-oc tile, 2 px-subtiles x 18 K-steps.
// ---------------------------------------------------------------------------
__global__ __launch_bounds__(256, 4) void deform_kernel(
    const unsigned short* __restrict__ xt,
    const float* __restrict__ ofs,
    const unsigned short* __restrict__ wbf,
    const float* __restrict__ b_dcn,
    float* __restrict__ out)
{
    const int f = blockIdx.y;
    const int t = f < 2 ? f : f + 1;
    const int p0 = blockIdx.x * 32;
    const int tid = threadIdx.x;

    __shared__ unsigned short smp[32 * SLDE];   // [pix][K'], K' = g*72+k*8+cg

    // ---- phase 1: sampling, one (g, pixel) task per thread ----
    {
        const int g = tid >> 5, pl = tid & 31;
        const int p = p0 + pl;
        const int y = p / 96, xx = p - y * 96;
        const unsigned short* xf = xt + (size_t)t * HWN * 64 + g * 8;
        const float* ob = ofs + (size_t)f * 144 * HWN + (size_t)g * 18 * HWN + p;
        float dy[9], dx[9];
        #pragma unroll
        for (int k = 0; k < 9; ++k) {           // 18 coalesced scalar loads
            dy[k] = ob[(size_t)(2 * k) * HWN];
            dx[k] = ob[(size_t)(2 * k + 1) * HWN];
        }
        unsigned short* srow = smp + pl * SLDE + g * 72;
        #pragma unroll
        for (int k = 0; k < 9; ++k) {
            const int r = k / 3, d = k - 3 * (k / 3);
            const float ys = (float)(y + r - 1) + dy[k];
            const float xs = (float)(xx + d - 1) + dx[k];
            const float y0f = floorf(ys), x0f = floorf(xs);
            const float wy = ys - y0f, wx = xs - x0f;
            const int y0 = (int)y0f, x0 = (int)x0f;
            const int y1 = y0 + 1, x1 = x0 + 1;
            const bool vy0 = (y0 >= 0) & (y0 < 96);
            const bool vy1 = (y1 >= 0) & (y1 < 96);
            const bool vx0 = (x0 >= 0) & (x0 < 96);
            const bool vx1 = (x1 >= 0) & (x1 < 96);
            const int yc0 = min(max(y0, 0), 95), yc1 = min(max(y1, 0), 95);
            const int xc0 = min(max(x0, 0), 95), xc1 = min(max(x1, 0), 95);
            const float w00 = (vy0 & vx0) ? (1.f - wy) * (1.f - wx) : 0.f;
            const float w01 = (vy0 & vx1) ? (1.f - wy) * wx : 0.f;
            const float w10 = (vy1 & vx0) ? wy * (1.f - wx) : 0.f;
            const float w11 = (vy1 & vx1) ? wy * wx : 0.f;
            bf16x8 c00 = *reinterpret_cast<const bf16x8*>(xf + (size_t)(yc0 * 96 + xc0) * 64);
            bf16x8 c01 = *reinterpret_cast<const bf16x8*>(xf + (size_t)(yc0 * 96 + xc1) * 64);
            bf16x8 c10 = *reinterpret_cast<const bf16x8*>(xf + (size_t)(yc1 * 96 + xc0) * 64);
            bf16x8 c11 = *reinterpret_cast<const bf16x8*>(xf + (size_t)(yc1 * 96 + xc1) * 64);
            bf16x8 pk;
            #pragma unroll
            for (int ch = 0; ch < 8; ++ch) {
                float v = w00 * bf2f((unsigned short)c00[ch]);
                v = fmaf(w01, bf2f((unsigned short)c01[ch]), v);
                v = fmaf(w10, bf2f((unsigned short)c10[ch]), v);
                v = fmaf(w11, bf2f((unsigned short)c11[ch]), v);
                pk[ch] = (short)f2bf(v);
            }
            *reinterpret_cast<bf16x8*>(srow + k * 8) = pk;   // 16B aligned
        }
    }
    __syncthreads();

    // ---- phase 2: MFMA. wave w = o-tile, px-subtiles pt=0,1 ----
    const int w = tid >> 6;
    const int l = tid & 63;
    const int o0 = w * 16;
    const int lr = l & 15, lg = l >> 4;

    bf16x8 afr[18];
    const unsigned short* wrow = wbf + (size_t)(o0 + lr) * 576 + lg * 8;
    #pragma unroll
    for (int s = 0; s < 18; ++s)
        afr[s] = *reinterpret_cast<const bf16x8*>(wrow + s * 32);

    f32x4 acc0 = {0.f, 0.f, 0.f, 0.f}, acc1 = {0.f, 0.f, 0.f, 0.f};
    const unsigned short* brow0 = smp + lr * SLDE + lg * 8;
    const unsigned short* brow1 = brow0 + 16 * SLDE;
    #pragma unroll
    for (int s = 0; s < 18; ++s) {
        bf16x8 b0 = *reinterpret_cast<const bf16x8*>(brow0 + s * 32);
        bf16x8 b1 = *reinterpret_cast<const bf16x8*>(brow1 + s * 32);
        acc0 = __builtin_amdgcn_mfma_f32_16x16x32_bf16(afr[s], b0, acc0, 0, 0, 0);
        acc1 = __builtin_amdgcn_mfma_f32_16x16x32_bf16(afr[s], b1, acc1, 0, 0, 0);
    }

    float* op = out + (size_t)t * PLN + p0;
    #pragma unroll
    for (int r = 0; r < 4; ++r) {
        const int o = o0 + lg * 4 + r;              // C/D: row=(lane>>4)*4+r
        const float bb = b_dcn[o];
        op[(size_t)o * HWN + lr] = acc0[r] + bb;              // col = lane&15
        op[(size_t)o * HWN + 16 + lr] = acc1[r] + bb;
    }
}

extern "C" void kernel_launch(void* const* d_in, const int* in_sizes, int n_in,
                              void* d_out, int out_size, void* d_ws, size_t ws_size,
                              hipStream_t stream) {
    const float* x     = (const float*)d_in[0];
    const float* w_off = (const float*)d_in[1];
    const float* b_off = (const float*)d_in[2];
    const float* w_dcn = (const float*)d_in[3];
    const float* b_dcn = (const float*)d_in[4];
    float* out = (float*)d_out;

    float* ofs          = (float*)d_ws;                        // [4][144][9216] f32, 21.2 MB
    unsigned short* xt  = (unsigned short*)(ofs + (size_t)4 * 144 * HWN); // [5][9216][64] bf16, 5.9 MB
    unsigned short* wbf = xt + (size_t)5 * HWN * 64;           // [64][576] bf16
    unsigned short* wcbf = wbf + (size_t)64 * 576;             // [2][144][576] bf16
    // ws total ~27.6 MB

    // feat transpose + center passthrough + weight reorders (y==5 slice)
    xprep_kernel<<<dim3(144, 6), 256, 0, stream>>>(x, w_dcn, w_off, xt, wbf, wcbf, out);

    // offset conv (both slabs fused), 32-px tiles, writes ofs for 4 frames
    conv_mfma_kernel<<<dim3(288, 4), 576, 0, stream>>>(xt, wcbf, b_off, ofs);

    // deformable sampling + projection, 32-px tiles
    deform_kernel<<<dim3(288, 4), 256, 0, stream>>>(xt, ofs, wbf, b_dcn, out);
}

// Round 11
// 83.188 us; speedup vs baseline: 2.4622x; 1.2744x over previous
//
#include <hip/hip_runtime.h>
#include <hip/hip_bf16.h>

#define HWN 9216              // 96*96
#define PLN (64 * HWN)        // one frame's feature plane (C=64)
#define SLDE 584              // LDS row stride (bf16 elems)

typedef __attribute__((ext_vector_type(8))) short bf16x8;
typedef __attribute__((ext_vector_type(4))) float f32x4;

__device__ __forceinline__ unsigned short f2bf(float v) {
    union { float f; unsigned u; } cv; cv.f = v;
    unsigned u = cv.u;
    u += 0x7fffu + ((u >> 16) & 1u);   // round-to-nearest-even
    return (unsigned short)(u >> 16);
}
__device__ __forceinline__ float bf2f(unsigned short b) {
    union { unsigned u; float f; } cv; cv.u = ((unsigned)b) << 16;
    return cv.f;
}

// ---------------------------------------------------------------------------
// y<5 : transpose x[t][c][p] f32 -> xt[t][p][64c] bf16 (+ center copy to out)
// y==5: weight reorders to K' = g*72 + k*8 + cg, bf16:
//       wbf[64][576] <- w_dcn; wcbf[2][144][576] <- w_off (slab0 neig, 1 ctr)
// ---------------------------------------------------------------------------
__global__ __launch_bounds__(256) void xprep_kernel(
    const float* __restrict__ x, const float* __restrict__ w_dcn,
    const float* __restrict__ w_off, unsigned short* __restrict__ xt,
    unsigned short* __restrict__ wbf, unsigned short* __restrict__ wcbf,
    float* __restrict__ out)
{
    const int t = blockIdx.y;
    const int tid = threadIdx.x;
    if (t == 5) {   // weight prep
        for (int idx = blockIdx.x * 256 + tid; idx < 64 * 576 + 2 * 144 * 576;
             idx += 144 * 256) {
            if (idx < 64 * 576) {
                int o = idx / 576, c = idx % 576;
                int g = c / 72, rem = c % 72, k = rem >> 3, cg = rem & 7;
                wbf[idx] = f2bf(w_dcn[o * 576 + (g * 8 + cg) * 9 + k]);
            } else {
                int i2 = idx - 64 * 576;
                int s = i2 / (144 * 576);
                int o = (i2 / 576) % 144;
                int kk = i2 % 576;
                int g = kk / 72, rem = kk % 72, k = rem >> 3, cg = rem & 7;
                wcbf[i2] = f2bf(w_off[(size_t)o * 1152
                                      + (size_t)(s * 64 + g * 8 + cg) * 9 + k]);
            }
        }
        return;
    }
    const int p0 = blockIdx.x * 64;
    __shared__ unsigned short tile[64][72];
    const float* in = x + (size_t)t * PLN;
    const bool isC = (t == 2);
    for (int idx = tid; idx < 4096; idx += 256) {
        int c = idx >> 6, p = idx & 63;
        float v = in[(size_t)c * HWN + p0 + p];
        tile[p][c] = f2bf(v);
        if (isC) out[(size_t)2 * PLN + (size_t)c * HWN + p0 + p] = v;
    }
    __syncthreads();
    unsigned short* xo = xt + ((size_t)t * HWN + p0) * 64;
    for (int task = tid; task < 512; task += 256) {
        int p = task >> 3, cb = task & 7;
        *reinterpret_cast<bf16x8*>(xo + p * 64 + cb * 8) =
            *reinterpret_cast<const bf16x8*>(&tile[p][cb * 8]);
    }
}

// ---------------------------------------------------------------------------
// Center-slab conv: wsC[144][9216] = W_ctr[144x576] * im2col(center).
// 576 thr (9 waves), 32-px tile, grid 288. Batched 4-granule staging.
// ---------------------------------------------------------------------------
__global__ __launch_bounds__(576, 2) void conv_center_kernel(
    const unsigned short* __restrict__ xt,
    const unsigned short* __restrict__ wcbf,
    float* __restrict__ wsC)
{
    const int p0 = blockIdx.x * 32;
    const int tid = threadIdx.x;
    const int w = tid >> 6, l = tid & 63;
    const int lr = l & 15, lg = l >> 4;

    __shared__ unsigned short smp[32 * SLDE];

    // ---- batched stage: 2304 granules, 4/thread (all loads in flight) ----
    {
        const unsigned short* xb = xt + (size_t)2 * HWN * 64;
        const bf16x8 bz = {0,0,0,0,0,0,0,0};
        bf16x8 stg[4]; int dst[4];
        #pragma unroll
        for (int i = 0; i < 4; ++i) {
            const int tsk = i * 576 + tid;          // 0..2303
            const int g = tsk & 7, pl = (tsk >> 3) & 31, k = tsk >> 8;
            const int p = p0 + pl;
            const int y = p / 96, xx = p - y * 96;
            const int r = k / 3, d = k - 3 * (k / 3);
            const int yy = y + r - 1, xw = xx + d - 1;
            const bool valid = (yy >= 0) & (yy < 96) & (xw >= 0) & (xw < 96);
            const int lin = min(max(yy, 0), 95) * 96 + min(max(xw, 0), 95);
            bf16x8 v = *reinterpret_cast<const bf16x8*>(xb + (size_t)lin * 64 + g * 8);
            stg[i] = valid ? v : bz;
            dst[i] = pl * SLDE + g * 72 + k * 8;
        }
        #pragma unroll
        for (int i = 0; i < 4; ++i)
            *reinterpret_cast<bf16x8*>(smp + dst[i]) = stg[i];
    }
    __syncthreads();

    // ---- MFMA: wave = 16-oc tile, 2 px-subtiles x 18 K-steps ----
    const unsigned short* wp = wcbf + (size_t)1 * 144 * 576
                               + (size_t)(w * 16 + lr) * 576 + lg * 8;
    bf16x8 afr[18];
    #pragma unroll
    for (int ss = 0; ss < 18; ++ss)
        afr[ss] = *reinterpret_cast<const bf16x8*>(wp + ss * 32);

    f32x4 acc[2] = {{0,0,0,0},{0,0,0,0}};
    #pragma unroll
    for (int pt = 0; pt < 2; ++pt) {
        const unsigned short* brow = smp + (pt * 16 + lr) * SLDE + lg * 8;
        #pragma unroll
        for (int ss = 0; ss < 18; ++ss) {
            bf16x8 b = *reinterpret_cast<const bf16x8*>(brow + ss * 32);
            acc[pt] = __builtin_amdgcn_mfma_f32_16x16x32_bf16(afr[ss], b, acc[pt], 0, 0, 0);
        }
    }
    #pragma unroll
    for (int pt = 0; pt < 2; ++pt) {
        const int px = p0 + pt * 16 + lr;
        #pragma unroll
        for (int r = 0; r < 4; ++r) {
            const int o = w * 16 + lg * 4 + r;   // C/D: row=(lane>>4)*4+r, col=lane&15
            wsC[(size_t)o * HWN + px] = acc[pt][r];
        }
    }
}

// ---------------------------------------------------------------------------
// Neighbor-slab conv: ofs[f] = W_neig * im2col(frame f) + wsC + b_off.
// 576 thr (9 waves), 64-px tile, grid (144,4). Batched 8-granule staging,
// single barrier per block. K=576.
// ---------------------------------------------------------------------------
__global__ __launch_bounds__(576, 2) void conv_neig_kernel(
    const unsigned short* __restrict__ xt,
    const unsigned short* __restrict__ wcbf,
    const float* __restrict__ b_off,
    const float* __restrict__ wsC,
    float* __restrict__ ofs)
{
    const int f = blockIdx.y;
    const int t = f < 2 ? f : f + 1;
    const int p0 = blockIdx.x * 64;
    const int tid = threadIdx.x;
    const int w = tid >> 6, l = tid & 63;
    const int lr = l & 15, lg = l >> 4;

    __shared__ unsigned short smp[64 * SLDE];

    // ---- batched stage: 4608 granules, 8/thread (all loads in flight) ----
    {
        const unsigned short* xb = xt + (size_t)t * HWN * 64;
        const bf16x8 bz = {0,0,0,0,0,0,0,0};
        bf16x8 stg[8]; int dst[8];
        #pragma unroll
        for (int i = 0; i < 8; ++i) {
            const int tsk = i * 576 + tid;          // 0..4607
            const int g = tsk & 7, pl = (tsk >> 3) & 63, k = tsk >> 9;
            const int p = p0 + pl;
            const int y = p / 96, xx = p - y * 96;
            const int r = k / 3, d = k - 3 * (k / 3);
            const int yy = y + r - 1, xw = xx + d - 1;
            const bool valid = (yy >= 0) & (yy < 96) & (xw >= 0) & (xw < 96);
            const int lin = min(max(yy, 0), 95) * 96 + min(max(xw, 0), 95);
            bf16x8 v = *reinterpret_cast<const bf16x8*>(xb + (size_t)lin * 64 + g * 8);
            stg[i] = valid ? v : bz;
            dst[i] = pl * SLDE + g * 72 + k * 8;
        }
        #pragma unroll
        for (int i = 0; i < 8; ++i)
            *reinterpret_cast<bf16x8*>(smp + dst[i]) = stg[i];
    }
    __syncthreads();

    // ---- MFMA: wave = 16-oc tile, 4 px-subtiles x 18 K-steps ----
    const unsigned short* wp = wcbf + (size_t)(w * 16 + lr) * 576 + lg * 8;
    bf16x8 afr[18];
    #pragma unroll
    for (int ss = 0; ss < 18; ++ss)
        afr[ss] = *reinterpret_cast<const bf16x8*>(wp + ss * 32);

    f32x4 acc[4] = {{0,0,0,0},{0,0,0,0},{0,0,0,0},{0,0,0,0}};
    #pragma unroll
    for (int pt = 0; pt < 4; ++pt) {
        const unsigned short* brow = smp + (pt * 16 + lr) * SLDE + lg * 8;
        #pragma unroll
        for (int ss = 0; ss < 18; ++ss) {
            bf16x8 b = *reinterpret_cast<const bf16x8*>(brow + ss * 32);
            acc[pt] = __builtin_amdgcn_mfma_f32_16x16x32_bf16(afr[ss], b, acc[pt], 0, 0, 0);
        }
    }

    float* of = ofs + (size_t)f * 144 * HWN;
    #pragma unroll
    for (int pt = 0; pt < 4; ++pt) {
        const int px = p0 + pt * 16 + lr;
        #pragma unroll
        for (int r = 0; r < 4; ++r) {
            const int o = w * 16 + lg * 4 + r;   // C/D: row=(lane>>4)*4+r, col=lane&15
            of[(size_t)o * HWN + px] = acc[pt][r] + wsC[(size_t)o * HWN + px] + b_off[o];
        }
    }
}

// ---------------------------------------------------------------------------
// Deform: LDS-staged sampling + MFMA projection. 256 thr (4 waves),
// 32-px tile, grid (288,4). Phase 1 uses a depth-2 tap pipeline: corners
// for tap k+1 are issued while tap k is lerped (all indices compile-time).
// ---------------------------------------------------------------------------
__global__ __launch_bounds__(256, 4) void deform_kernel(
    const unsigned short* __restrict__ xt,
    const float* __restrict__ ofs,
    const unsigned short* __restrict__ wbf,
    const float* __restrict__ b_dcn,
    float* __restrict__ out)
{
    const int f = blockIdx.y;
    const int t = f < 2 ? f : f + 1;
    const int p0 = blockIdx.x * 32;
    const int tid = threadIdx.x;

    __shared__ unsigned short smp[32 * SLDE];   // [pix][K'], K' = g*72+k*8+cg

    // ---- phase 1: sampling, one (g, pixel) task per thread ----
    {
        const int g = tid >> 5, pl = tid & 31;
        const int p = p0 + pl;
        const int y = p / 96, xx = p - y * 96;
        const unsigned short* xf = xt + (size_t)t * HWN * 64 + g * 8;
        const float* ob = ofs + (size_t)f * 144 * HWN + (size_t)g * 18 * HWN + p;
        float dy[9], dx[9];
        #pragma unroll
        for (int k = 0; k < 9; ++k) {           // 18 coalesced scalar loads
            dy[k] = ob[(size_t)(2 * k) * HWN];
            dx[k] = ob[(size_t)(2 * k + 1) * HWN];
        }
        unsigned short* srow = smp + pl * SLDE + g * 72;

        bf16x8 cc[2][4];
        float  ww[2][4];
        auto prep = [&](int k, int buf) {
            const int r = k / 3, d = k - 3 * (k / 3);
            const float ys = (float)(y + r - 1) + dy[k];
            const float xs = (float)(xx + d - 1) + dx[k];
            const float y0f = floorf(ys), x0f = floorf(xs);
            const float wy = ys - y0f, wx = xs - x0f;
            const int y0 = (int)y0f, x0 = (int)x0f;
            const int y1 = y0 + 1, x1 = x0 + 1;
            const bool vy0 = (y0 >= 0) & (y0 < 96);
            const bool vy1 = (y1 >= 0) & (y1 < 96);
            const bool vx0 = (x0 >= 0) & (x0 < 96);
            const bool vx1 = (x1 >= 0) & (x1 < 96);
            const int yc0 = min(max(y0, 0), 95), yc1 = min(max(y1, 0), 95);
            const int xc0 = min(max(x0, 0), 95), xc1 = min(max(x1, 0), 95);
            ww[buf][0] = (vy0 & vx0) ? (1.f - wy) * (1.f - wx) : 0.f;
            ww[buf][1] = (vy0 & vx1) ? (1.f - wy) * wx : 0.f;
            ww[buf][2] = (vy1 & vx0) ? wy * (1.f - wx) : 0.f;
            ww[buf][3] = (vy1 & vx1) ? wy * wx : 0.f;
            cc[buf][0] = *reinterpret_cast<const bf16x8*>(xf + (size_t)(yc0 * 96 + xc0) * 64);
            cc[buf][1] = *reinterpret_cast<const bf16x8*>(xf + (size_t)(yc0 * 96 + xc1) * 64);
            cc[buf][2] = *reinterpret_cast<const bf16x8*>(xf + (size_t)(yc1 * 96 + xc0) * 64);
            cc[buf][3] = *reinterpret_cast<const bf16x8*>(xf + (size_t)(yc1 * 96 + xc1) * 64);
        };

        prep(0, 0);
        #pragma unroll
        for (int k = 0; k < 9; ++k) {
            if (k < 8) prep(k + 1, (k + 1) & 1);     // prefetch next tap
            const int b = k & 1;
            bf16x8 pk;
            #pragma unroll
            for (int ch = 0; ch < 8; ++ch) {
                float v = ww[b][0] * bf2f((unsigned short)cc[b][0][ch]);
                v = fmaf(ww[b][1], bf2f((unsigned short)cc[b][1][ch]), v);
                v = fmaf(ww[b][2], bf2f((unsigned short)cc[b][2][ch]), v);
                v = fmaf(ww[b][3], bf2f((unsigned short)cc[b][3][ch]), v);
                pk[ch] = (short)f2bf(v);
            }
            *reinterpret_cast<bf16x8*>(srow + k * 8) = pk;   // 16B aligned
        }
    }
    __syncthreads();

    // ---- phase 2: MFMA. wave w = o-tile, px-subtiles pt=0,1 ----
    const int w = tid >> 6;
    const int l = tid & 63;
    const int o0 = w * 16;
    const int lr = l & 15, lg = l >> 4;

    bf16x8 afr[18];
    const unsigned short* wrow = wbf + (size_t)(o0 + lr) * 576 + lg * 8;
    #pragma unroll
    for (int s = 0; s < 18; ++s)
        afr[s] = *reinterpret_cast<const bf16x8*>(wrow + s * 32);

    f32x4 acc0 = {0.f, 0.f, 0.f, 0.f}, acc1 = {0.f, 0.f, 0.f, 0.f};
    const unsigned short* brow0 = smp + lr * SLDE + lg * 8;
    const unsigned short* brow1 = brow0 + 16 * SLDE;
    #pragma unroll
    for (int s = 0; s < 18; ++s) {
        bf16x8 b0 = *reinterpret_cast<const bf16x8*>(brow0 + s * 32);
        bf16x8 b1 = *reinterpret_cast<const bf16x8*>(brow1 + s * 32);
        acc0 = __builtin_amdgcn_mfma_f32_16x16x32_bf16(afr[s], b0, acc0, 0, 0, 0);
        acc1 = __builtin_amdgcn_mfma_f32_16x16x32_bf16(afr[s], b1, acc1, 0, 0, 0);
    }

    float* op = out + (size_t)t * PLN + p0;
    #pragma unroll
    for (int r = 0; r < 4; ++r) {
        const int o = o0 + lg * 4 + r;              // C/D: row=(lane>>4)*4+r
        const float bb = b_dcn[o];
        op[(size_t)o * HWN + lr] = acc0[r] + bb;              // col = lane&15
        op[(size_t)o * HWN + 16 + lr] = acc1[r] + bb;
    }
}

extern "C" void kernel_launch(void* const* d_in, const int* in_sizes, int n_in,
                              void* d_out, int out_size, void* d_ws, size_t ws_size,
                              hipStream_t stream) {
    const float* x     = (const float*)d_in[0];
    const float* w_off = (const float*)d_in[1];
    const float* b_off = (const float*)d_in[2];
    const float* w_dcn = (const float*)d_in[3];
    const float* b_dcn = (const float*)d_in[4];
    float* out = (float*)d_out;

    float* ofs          = (float*)d_ws;                        // [4][144][9216] f32, 21.2 MB
    unsigned short* xt  = (unsigned short*)(ofs + (size_t)4 * 144 * HWN); // [5][9216][64] bf16, 5.9 MB
    unsigned short* wbf = xt + (size_t)5 * HWN * 64;           // [64][576] bf16
    unsigned short* wcbf = wbf + (size_t)64 * 576;             // [2][144][576] bf16
    float* wsC = (float*)(wcbf + (size_t)2 * 144 * 576);       // [144][9216] f32, 5.3 MB
    // ws total ~32.9 MB

    // feat transpose + center passthrough + weight reorders (y==5 slice)
    xprep_kernel<<<dim3(144, 6), 256, 0, stream>>>(x, w_dcn, w_off, xt, wbf, wcbf, out);

    // center-slab conv (frame-invariant, computed once)
    conv_center_kernel<<<288, 576, 0, stream>>>(xt, wcbf, wsC);

    // neighbor-slab conv + wsC + bias -> ofs for 4 frames
    conv_neig_kernel<<<dim3(144, 4), 576, 0, stream>>>(xt, wcbf, b_off, wsC, ofs);

    // deformable sampling + projection
    deform_kernel<<<dim3(288, 4), 256, 0, stream>>>(xt, ofs, wbf, b_dcn, out);
}